// Round 16
// baseline (212.982 us; speedup 1.0000x reference)
//
#include <hip/hip_runtime.h>
#include <hip/hip_bf16.h>

#define NN 100000
#define NE 1600000
#define NG 128
#define FIN 128
#define HID 32
#define NCLS 10

#define EG4 (NE / 4)           // 400000 int4 edge groups

// atomic-free CSR build
#define NSL 32                 // edge-list slices
#define GPS (EG4 / NSL)        // 12500 int4 groups per slice
#define RS 8                   // node sub-ranges (bid&7 -> XCD-local csr writes)
#define SUBN (NN / RS)         // 12500 nodes per range -> 50KB LDS counters
#define CSRGRID (RS * NSL)     // 256 blocks
#define CSR_T 1024             // 16 waves/CU -> latency hiding

#define PAD 16                 // CSR rows padded to multiple of 16 (zero-row idx NN)
#define NEP (NE + NN * PAD + 64)   // padded csr capacity + prefetch slack

#define SCAN_B 1024
#define NB ((NN + SCAN_B - 1) / SCAN_B)      // 98

#define POOL_CHUNK 512
#define POOL_SEG 16
#define POOL_GSPAN 32
#define POOL_GRID ((NN + POOL_CHUNK - 1) / POOL_CHUNK)

// GEMM0 MFMA tiling
#define G0_NODES 64
#define G0_GRID ((NN + G0_NODES - 1) / G0_NODES)
#define XPAD 136

// agg grids
#define AGG_GRID (NN / 4)      // final agg: 25000 blocks x 4 waves (1 node/wave)
#define AGF_NPB 8              // fused agg: 8 nodes per 512-thread block
#define AGF_GRID (NN / AGF_NPB)    // 12500 blocks

typedef int int4v __attribute__((ext_vector_type(4)));
typedef __attribute__((ext_vector_type(8))) short short8;
typedef __attribute__((ext_vector_type(4))) float f32x4;

__device__ inline unsigned short f2bf(float f) {
    unsigned int u = __float_as_uint(f);
    unsigned int r = u + 0x7FFFu + ((u >> 16) & 1u);   // RNE
    return (unsigned short)(r >> 16);
}
__device__ inline float bf2f(unsigned short v) {
    return __uint_as_float(((unsigned int)v) << 16);
}

// ---------------- init: zero pooling accumulators + zero pad-rows ----------------
__global__ void k_init(float* __restrict__ gsum, float* __restrict__ gcnt,
                       unsigned short* __restrict__ tzero,
                       unsigned short* __restrict__ hzero) {
    int i = blockIdx.x * blockDim.x + threadIdx.x;
    if (i < NG * HID) gsum[i] = 0.f;
    if (i < NG) gcnt[i] = 0.f;
    if (i < HID) { tzero[i] = 0; hzero[i] = 0; }   // row NN of both gather buffers
}

// ------- hist: LDS count per node-range per slice; u8 partial store. -------
__global__ __launch_bounds__(CSR_T) void k_hist3(const int* __restrict__ dst,
                                                 unsigned char* __restrict__ partial) {
    const int r = blockIdx.x & (RS - 1);
    const int s = blockIdx.x >> 3;
    const int node0 = r * SUBN;
    __shared__ int lcnt[SUBN];                 // 50 KB
    for (int k = threadIdx.x; k < SUBN; k += CSR_T) lcnt[k] = 0;
    __syncthreads();
    const int g1 = (s + 1) * GPS;
    for (int g = s * GPS + threadIdx.x; g < g1; g += CSR_T) {
        const int4v d = *((const int4v*)dst + g);
        unsigned k;
        k = (unsigned)(d.x - node0); if (k < SUBN) atomicAdd(&lcnt[k], 1);
        k = (unsigned)(d.y - node0); if (k < SUBN) atomicAdd(&lcnt[k], 1);
        k = (unsigned)(d.z - node0); if (k < SUBN) atomicAdd(&lcnt[k], 1);
        k = (unsigned)(d.w - node0); if (k < SUBN) atomicAdd(&lcnt[k], 1);
    }
    __syncthreads();
    for (int k = threadIdx.x; k < SUBN; k += CSR_T)
        partial[s * NN + node0 + k] = (unsigned char)lcnt[k];
}

// ------- scanA: fold NSL u8 partials/node -> deg (+ in-place exclusive prefix
//         over slices), dinv, deg[], block-exclusive scan of PADDED degrees -------
__global__ void k_scanA(unsigned char* __restrict__ partial, int* __restrict__ row_ptr,
                        int* __restrict__ bsum, float* __restrict__ dinv,
                        int* __restrict__ deg) {
    __shared__ int lds[SCAN_B];
    int i = blockIdx.x * SCAN_B + threadIdx.x;
    int pv = 0;
    if (i < NN) {
        int run = 0;
#pragma unroll
        for (int s = 0; s < NSL; s++) {
            int c = partial[s * NN + i];
            partial[s * NN + i] = (unsigned char)run;   // exclusive prefix (<= deg <= 255)
            run += c;
        }
        deg[i] = run;
        dinv[i] = rsqrtf((float)run + 1.0f);
        pv = (run + PAD - 1) & ~(PAD - 1);              // padded degree
    }
    lds[threadIdx.x] = pv;
    __syncthreads();
    int val = pv;
    for (int off = 1; off < SCAN_B; off <<= 1) {
        int u = 0;
        if ((int)threadIdx.x >= off) u = lds[threadIdx.x - off];
        __syncthreads();
        if ((int)threadIdx.x >= off) { val += u; lds[threadIdx.x] = val; }
        __syncthreads();
    }
    if (i < NN) row_ptr[i] = val - pv;
    if (threadIdx.x == SCAN_B - 1) bsum[blockIdx.x] = val;
}

// ---------------- scanB: scan block sums ----------------
__global__ void k_scanB(int* __restrict__ bsum) {
    __shared__ int lds[128];
    int t = threadIdx.x;
    int v = (t < NB) ? bsum[t] : 0;
    lds[t] = v;
    __syncthreads();
    int val = v;
    for (int off = 1; off < 128; off <<= 1) {
        int u = 0;
        if (t >= off) u = lds[t - off];
        __syncthreads();
        if (t >= off) { val += u; lds[t] = val; }
        __syncthreads();
    }
    if (t < NB) bsum[t] = val - v;
}

// ------- scanC: add block offsets; fix row_ptr[NN]; fill pad slots (fused k_pad) ----
__global__ void k_scanC(int* __restrict__ row_ptr, const int* __restrict__ bsum,
                        const int* __restrict__ deg, int* __restrict__ csr_src) {
    int i = blockIdx.x * SCAN_B + threadIdx.x;
    if (i < NN) {
        int r = row_ptr[i] + bsum[blockIdx.x];
        row_ptr[i] = r;
        int d = deg[i];
        int pd = (d + PAD - 1) & ~(PAD - 1);
        if (i == NN - 1) row_ptr[NN] = r + pd;
        for (int j = r + d; j < r + pd; j++) csr_src[j] = NN;   // pad -> zero row
    }
}

// ------- scatter: LDS cursor = row_ptr + u8 slice-prefix; LDS atomics only -------
__global__ __launch_bounds__(CSR_T) void k_scat3(const int* __restrict__ src,
                                                 const int* __restrict__ dst,
                                                 const int* __restrict__ row_ptr,
                                                 const unsigned char* __restrict__ pref,
                                                 int* __restrict__ csr_src) {
    const int r = blockIdx.x & (RS - 1);
    const int s = blockIdx.x >> 3;
    const int node0 = r * SUBN;
    __shared__ int lcur[SUBN];                 // 50 KB
    for (int k = threadIdx.x; k < SUBN; k += CSR_T)
        lcur[k] = row_ptr[node0 + k] + (int)pref[s * NN + node0 + k];
    __syncthreads();
    const int g1 = (s + 1) * GPS;
    for (int g = s * GPS + threadIdx.x; g < g1; g += CSR_T) {
        const int4v d = *((const int4v*)dst + g);
        const int4v sx = *((const int4v*)src + g);
        unsigned k;
        k = (unsigned)(d.x - node0); if (k < SUBN) { int p = atomicAdd(&lcur[k], 1); csr_src[p] = sx.x; }
        k = (unsigned)(d.y - node0); if (k < SUBN) { int p = atomicAdd(&lcur[k], 1); csr_src[p] = sx.y; }
        k = (unsigned)(d.z - node0); if (k < SUBN) { int p = atomicAdd(&lcur[k], 1); csr_src[p] = sx.z; }
        k = (unsigned)(d.w - node0); if (k < SUBN) { int p = atomicAdd(&lcur[k], 1); csr_src[p] = sx.w; }
    }
}

// ---------------- layer-0 GEMM via bf16 MFMA: t = bf16((x @ W0) * dinv) --------
__global__ void k_gemm0(const float* __restrict__ x, const float* __restrict__ W,
                        const float* __restrict__ dinv, unsigned short* __restrict__ t) {
    __shared__ __align__(16) unsigned short x_lds[G0_NODES][XPAD];
    __shared__ __align__(16) unsigned short wt_lds[HID][XPAD];
    const int tid = threadIdx.x;
    const int node0 = blockIdx.x * G0_NODES;

#pragma unroll
    for (int r = 0; r < 8; r++) {
        int q = tid + 256 * r;
        int row = q >> 5;
        int c4 = q & 31;
        float4 xv = {0.f, 0.f, 0.f, 0.f};
        int node = node0 + row;
        if (node < NN) xv = ((const float4*)(x + (size_t)node * FIN))[c4];
        ushort4 b;
        b.x = f2bf(xv.x); b.y = f2bf(xv.y); b.z = f2bf(xv.z); b.w = f2bf(xv.w);
        *(ushort4*)&x_lds[row][c4 * 4] = b;
    }
#pragma unroll
    for (int r = 0; r < 16; r++) {
        int q = tid + 256 * r;
        int k = q >> 5, n = q & 31;
        wt_lds[n][k] = f2bf(W[q]);
    }
    __syncthreads();

    const int w = tid >> 6;
    const int lane = tid & 63;
    const int row = lane & 15;
    const int kg = lane >> 4;
    const int w16 = w * 16;

    f32x4 acc0 = {0.f, 0.f, 0.f, 0.f};
    f32x4 acc1 = {0.f, 0.f, 0.f, 0.f};
#pragma unroll
    for (int s = 0; s < 4; s++) {
        short8 a  = *(const short8*)&x_lds[w16 + row][s * 32 + kg * 8];
        short8 b0 = *(const short8*)&wt_lds[row][s * 32 + kg * 8];
        short8 b1 = *(const short8*)&wt_lds[16 + row][s * 32 + kg * 8];
        acc0 = __builtin_amdgcn_mfma_f32_16x16x32_bf16(a, b0, acc0, 0, 0, 0);
        acc1 = __builtin_amdgcn_mfma_f32_16x16x32_bf16(a, b1, acc1, 0, 0, 0);
    }

    const int f = lane & 15;
#pragma unroll
    for (int j = 0; j < 4; j++) {
        int node = node0 + w16 + kg * 4 + j;
        if (node < NN) {
            float di = dinv[node];
            t[(size_t)node * HID + f]      = f2bf(acc0[j] * di);
            t[(size_t)node * HID + 16 + f] = f2bf(acc1[j] * di);
        }
    }
}

// ------- fused agg v2: 512 thr = 8 waves = 8 nodes. Per wave: dword feature-pair
//         gathers with 2-DEEP pipelined windows (two gather sets in flight).
//         h tile -> LDS -> wave 0 computes t' = bf16((h @ Wn) * dinv), 2 MFMAs. ----
__global__ __launch_bounds__(512, 8) void k_aggf(const unsigned short* __restrict__ t,
                                                 const int* __restrict__ row_ptr,
                                                 const int* __restrict__ csr_src,
                                                 const float* __restrict__ dinv,
                                                 const float* __restrict__ b,
                                                 const float* __restrict__ Wn,
                                                 unsigned short* __restrict__ hout) {
    __shared__ __align__(16) unsigned short wt[HID][HID];   // W^T: wt[n][k], 2KB
    __shared__ __align__(16) unsigned hlds[16 * 16];        // 16 rows x 16 dwords, 1KB
    // stage W transposed, conflict-free: fast index k = q&31 (2B stride, 2-way=free)
    for (int q = threadIdx.x; q < HID * HID; q += 512) {
        int n = q >> 5, k = q & 31;
        wt[n][k] = f2bf(Wn[k * HID + n]);
    }
    if (threadIdx.x < 128) hlds[128 + threadIdx.x] = 0;     // zero A-rows 8..15

    const int wave = threadIdx.x >> 6;                 // 0..7
    const int wid = blockIdx.x * AGF_NPB + wave;       // node = wave id
    const int lane = threadIdx.x & 63;
    const int fp = lane & 15;                          // feature pair
    const int sub = lane >> 4;                         // edge subset 0..3
    const int beg = row_ptr[wid], end = row_ptr[wid + 1];
    const unsigned* twp = (const unsigned*)t;

    float accLo = 0.f, accHi = 0.f;
    if (sub == 0) {                                    // self term
        unsigned u = twp[(size_t)wid * 16 + fp];
        accLo = __uint_as_float(u << 16);
        accHi = __uint_as_float(u & 0xFFFF0000u);
    }

    const int nwin = (end - beg) >> 4;
    int e = beg + sub * 4;
    int4v iaC = {0, 0, 0, 0}, iaN = {0, 0, 0, 0};
    if (nwin > 0) iaC = *(const int4v*)(csr_src + e);
    if (nwin > 1) iaN = *(const int4v*)(csr_src + e + 16);
    unsigned c0 = 0, c1 = 0, c2 = 0, c3 = 0;
    if (nwin > 0) {
        c0 = twp[(size_t)iaC.x * 16 + fp];
        c1 = twp[(size_t)iaC.y * 16 + fp];
        c2 = twp[(size_t)iaC.z * 16 + fp];
        c3 = twp[(size_t)iaC.w * 16 + fp];
    }
    for (int w = 0; w < nwin; w++) {
        unsigned n0 = 0, n1 = 0, n2 = 0, n3 = 0;
        if (w + 1 < nwin) {                            // issue NEXT window now
            n0 = twp[(size_t)iaN.x * 16 + fp];
            n1 = twp[(size_t)iaN.y * 16 + fp];
            n2 = twp[(size_t)iaN.z * 16 + fp];
            n3 = twp[(size_t)iaN.w * 16 + fp];
        }
        int4v iaP = iaN;
        if (w + 2 < nwin) iaP = *(const int4v*)(csr_src + e + 32);
        accLo += __uint_as_float(c0 << 16);
        accHi += __uint_as_float(c0 & 0xFFFF0000u);
        accLo += __uint_as_float(c1 << 16);
        accHi += __uint_as_float(c1 & 0xFFFF0000u);
        accLo += __uint_as_float(c2 << 16);
        accHi += __uint_as_float(c2 & 0xFFFF0000u);
        accLo += __uint_as_float(c3 << 16);
        accHi += __uint_as_float(c3 & 0xFFFF0000u);
        c0 = n0; c1 = n1; c2 = n2; c3 = n3;
        iaN = iaP;
        e += 16;
    }
    accLo += __shfl_xor(accLo, 16, 64);
    accHi += __shfl_xor(accHi, 16, 64);
    accLo += __shfl_xor(accLo, 32, 64);
    accHi += __shfl_xor(accHi, 32, 64);

    if (lane < 16) {                                   // h (post relu+bias) -> LDS tile
        const float di = dinv[wid];
        float hLo = fmaxf(fmaf(accLo, di, b[2 * fp]), 0.f);
        float hHi = fmaxf(fmaf(accHi, di, b[2 * fp + 1]), 0.f);
        hlds[wave * 16 + fp] = (unsigned)f2bf(hLo) | ((unsigned)f2bf(hHi) << 16);
    }
    __syncthreads();
    if (threadIdx.x >= 64) return;                     // wave 0 does the block GEMM

    const int row = lane & 15;                         // A-row (node) / D-col (feature)
    const int kg = lane >> 4;
    short8 a  = *(const short8*)((const unsigned short*)hlds + row * 32 + kg * 8);
    short8 b0 = *(const short8*)&wt[row][kg * 8];
    short8 b1 = *(const short8*)&wt[16 + row][kg * 8];
    f32x4 d0 = {0.f, 0.f, 0.f, 0.f};
    f32x4 d1 = {0.f, 0.f, 0.f, 0.f};
    d0 = __builtin_amdgcn_mfma_f32_16x16x32_bf16(a, b0, d0, 0, 0, 0);
    d1 = __builtin_amdgcn_mfma_f32_16x16x32_bf16(a, b1, d1, 0, 0, 0);
    if (kg >= 2) return;                               // rows 8..15 are zero pad
    const int node0 = blockIdx.x * AGF_NPB;
#pragma unroll
    for (int j = 0; j < 4; j++) {
        int node = node0 + kg * 4 + j;
        float dv = dinv[node];
        hout[(size_t)node * HID + row]      = f2bf(d0[j] * dv);
        hout[(size_t)node * HID + 16 + row] = f2bf(d1[j] * dv);
    }
}

// ------- final agg: one node/wave; 2-deep pipelined windows; bf16 packed out. ----
__global__ __launch_bounds__(256, 8) void k_agga(const unsigned short* __restrict__ t,
                                                 const int* __restrict__ row_ptr,
                                                 const int* __restrict__ csr_src,
                                                 const float* __restrict__ dinv,
                                                 const float* __restrict__ b,
                                                 unsigned short* __restrict__ hout) {
    const int wid = (blockIdx.x * 256 + threadIdx.x) >> 6;
    if (wid >= NN) return;
    const int lane = threadIdx.x & 63;
    const int fp = lane & 15;
    const int sub = lane >> 4;
    const int beg = row_ptr[wid], end = row_ptr[wid + 1];
    const unsigned* tw = (const unsigned*)t;

    float accLo = 0.f, accHi = 0.f;
    if (sub == 0) {
        unsigned u = tw[(size_t)wid * 16 + fp];
        accLo = __uint_as_float(u << 16);
        accHi = __uint_as_float(u & 0xFFFF0000u);
    }

    const int nwin = (end - beg) >> 4;
    int e = beg + sub * 4;
    int4v iaC = {0, 0, 0, 0}, iaN = {0, 0, 0, 0};
    if (nwin > 0) iaC = *(const int4v*)(csr_src + e);
    if (nwin > 1) iaN = *(const int4v*)(csr_src + e + 16);
    unsigned c0 = 0, c1 = 0, c2 = 0, c3 = 0;
    if (nwin > 0) {
        c0 = tw[(size_t)iaC.x * 16 + fp];
        c1 = tw[(size_t)iaC.y * 16 + fp];
        c2 = tw[(size_t)iaC.z * 16 + fp];
        c3 = tw[(size_t)iaC.w * 16 + fp];
    }
    for (int w = 0; w < nwin; w++) {
        unsigned n0 = 0, n1 = 0, n2 = 0, n3 = 0;
        if (w + 1 < nwin) {
            n0 = tw[(size_t)iaN.x * 16 + fp];
            n1 = tw[(size_t)iaN.y * 16 + fp];
            n2 = tw[(size_t)iaN.z * 16 + fp];
            n3 = tw[(size_t)iaN.w * 16 + fp];
        }
        int4v iaP = iaN;
        if (w + 2 < nwin) iaP = *(const int4v*)(csr_src + e + 32);
        accLo += __uint_as_float(c0 << 16);
        accHi += __uint_as_float(c0 & 0xFFFF0000u);
        accLo += __uint_as_float(c1 << 16);
        accHi += __uint_as_float(c1 & 0xFFFF0000u);
        accLo += __uint_as_float(c2 << 16);
        accHi += __uint_as_float(c2 & 0xFFFF0000u);
        accLo += __uint_as_float(c3 << 16);
        accHi += __uint_as_float(c3 & 0xFFFF0000u);
        c0 = n0; c1 = n1; c2 = n2; c3 = n3;
        iaN = iaP;
        e += 16;
    }
    accLo += __shfl_xor(accLo, 16, 64);
    accHi += __shfl_xor(accHi, 16, 64);
    accLo += __shfl_xor(accLo, 32, 64);
    accHi += __shfl_xor(accHi, 32, 64);
    if (sub == 0) {
        float di = dinv[wid];
        float rLo = fmaxf(fmaf(accLo, di, b[2 * fp]), 0.f);
        float rHi = fmaxf(fmaf(accHi, di, b[2 * fp + 1]), 0.f);
        unsigned out = (unsigned)f2bf(rLo) | ((unsigned)f2bf(rHi) << 16);
        ((unsigned*)hout)[(size_t)wid * 16 + fp] = out;
    }
}

// ---------------- pooling (bf16 in): register-segment accumulate -> LDS bins ----
__global__ void k_pool2(const unsigned short* __restrict__ h, const int* __restrict__ batch,
                        float* __restrict__ gsum, float* __restrict__ gcnt) {
    __shared__ float lacc[POOL_GSPAN][HID];
    __shared__ float lcnt[POOL_GSPAN];
    __shared__ int s_gmin;
    const int chunk_start = blockIdx.x * POOL_CHUNK;

    for (int j = threadIdx.x; j < POOL_GSPAN * HID; j += 256) ((float*)lacc)[j] = 0.f;
    if (threadIdx.x < POOL_GSPAN) lcnt[threadIdx.x] = 0.f;
    if (threadIdx.x == 0) {
        int cs = chunk_start < NN ? chunk_start : NN - 1;
        s_gmin = batch[cs];
    }
    __syncthreads();
    const int gmin = s_gmin;

    const int seg = threadIdx.x >> 3;
    const int l = (threadIdx.x & 7) * 4;
    const int i0 = chunk_start + seg * POOL_SEG;

    float4 acc = {0.f, 0.f, 0.f, 0.f};
    float cnt = 0.f;
    int cur_g = -1;

    for (int k = 0; k < POOL_SEG; k++) {
        int i = i0 + k;
        if (i >= NN) break;
        int g = batch[i];
        if (g != cur_g) {
            if (cur_g >= 0) {
                int bin = cur_g - gmin;
                if (bin >= 0 && bin < POOL_GSPAN) {
                    atomicAdd(&lacc[bin][l + 0], acc.x);
                    atomicAdd(&lacc[bin][l + 1], acc.y);
                    atomicAdd(&lacc[bin][l + 2], acc.z);
                    atomicAdd(&lacc[bin][l + 3], acc.w);
                    if (l == 0) atomicAdd(&lcnt[bin], cnt);
                } else {
                    atomicAdd(&gsum[cur_g * HID + l + 0], acc.x);
                    atomicAdd(&gsum[cur_g * HID + l + 1], acc.y);
                    atomicAdd(&gsum[cur_g * HID + l + 2], acc.z);
                    atomicAdd(&gsum[cur_g * HID + l + 3], acc.w);
                    if (l == 0) atomicAdd(&gcnt[cur_g], cnt);
                }
            }
            cur_g = g;
            acc.x = acc.y = acc.z = acc.w = 0.f;
            cnt = 0.f;
        }
        const ushort4 v = *(const ushort4*)&h[(size_t)i * HID + l];
        acc.x += bf2f(v.x); acc.y += bf2f(v.y);
        acc.z += bf2f(v.z); acc.w += bf2f(v.w);
        cnt += 1.f;
    }
    if (cur_g >= 0) {
        int bin = cur_g - gmin;
        if (bin >= 0 && bin < POOL_GSPAN) {
            atomicAdd(&lacc[bin][l + 0], acc.x);
            atomicAdd(&lacc[bin][l + 1], acc.y);
            atomicAdd(&lacc[bin][l + 2], acc.z);
            atomicAdd(&lacc[bin][l + 3], acc.w);
            if (l == 0) atomicAdd(&lcnt[bin], cnt);
        } else {
            atomicAdd(&gsum[cur_g * HID + l + 0], acc.x);
            atomicAdd(&gsum[cur_g * HID + l + 1], acc.y);
            atomicAdd(&gsum[cur_g * HID + l + 2], acc.z);
            atomicAdd(&gsum[cur_g * HID + l + 3], acc.w);
            if (l == 0) atomicAdd(&gcnt[cur_g], cnt);
        }
    }
    __syncthreads();

    for (int j = threadIdx.x; j < POOL_GSPAN * HID; j += 256) {
        int bin = j / HID, f = j % HID;
        int g = gmin + bin;
        float v = lacc[bin][f];
        if (g < NG && v != 0.f) atomicAdd(&gsum[g * HID + f], v);
    }
    if (threadIdx.x < POOL_GSPAN) {
        int g = gmin + threadIdx.x;
        float c = lcnt[threadIdx.x];
        if (g < NG && c != 0.f) atomicAdd(&gcnt[g], c);
    }
}

// ---------------- classifier + log_softmax ----------------
__global__ void k_classify(const float* __restrict__ gsum, const float* __restrict__ gcnt,
                           const float* __restrict__ Wl, const float* __restrict__ bl,
                           float* __restrict__ out) {
    __shared__ float w[HID * NCLS];
    __shared__ float bb[NCLS];
    int t = threadIdx.x;
    for (int j = t; j < HID * NCLS; j += blockDim.x) w[j] = Wl[j];
    if (t < NCLS) bb[t] = bl[t];
    __syncthreads();
    if (t >= NG) return;
    float c = gcnt[t];
    c = c > 1.f ? c : 1.f;
    float p[HID];
#pragma unroll
    for (int k = 0; k < HID; k++) p[k] = gsum[t * HID + k] / c;
    float lg[NCLS];
    float m = -1e30f;
#pragma unroll
    for (int c2 = 0; c2 < NCLS; c2++) {
        float a = bb[c2];
#pragma unroll
        for (int k = 0; k < HID; k++) a = fmaf(p[k], w[k * NCLS + c2], a);
        a = a > 0.f ? a : 0.f;
        lg[c2] = a;
        m = fmaxf(m, a);
    }
    float s = 0.f;
#pragma unroll
    for (int c2 = 0; c2 < NCLS; c2++) s += expf(lg[c2] - m);
    float ls = logf(s);
#pragma unroll
    for (int c2 = 0; c2 < NCLS; c2++) out[t * NCLS + c2] = lg[c2] - m - ls;
}

extern "C" void kernel_launch(void* const* d_in, const int* in_sizes, int n_in,
                              void* d_out, int out_size, void* d_ws, size_t ws_size,
                              hipStream_t stream) {
    const float* x  = (const float*)d_in[0];
    const int* ei   = (const int*)d_in[1];
    const int* batch = (const int*)d_in[2];
    const float* W0 = (const float*)d_in[3];
    const float* b0 = (const float*)d_in[4];
    const float* W1 = (const float*)d_in[5];
    const float* b1 = (const float*)d_in[6];
    const float* W2 = (const float*)d_in[7];
    const float* b2 = (const float*)d_in[8];
    const float* Wl = (const float*)d_in[9];
    const float* bl = (const float*)d_in[10];
    float* out = (float*)d_out;

    const int* esrc = ei;
    const int* edst = ei + NE;

    char* ws = (char*)d_ws;
    size_t off = 0;
    auto alloc = [&](size_t bytes) -> void* {
        void* p = ws + off;
        off = (off + bytes + 511) & ~(size_t)511;
        return p;
    };
    int*   row_ptr = (int*)alloc((NN + 1) * sizeof(int));
    float* dinv    = (float*)alloc(NN * sizeof(float));
    int*   deg     = (int*)alloc(NN * sizeof(int));
    int*   bsum    = (int*)alloc(256 * sizeof(int));
    int*   csr_src = (int*)alloc((size_t)NEP * sizeof(int));
    unsigned short* tbuf = (unsigned short*)alloc((size_t)(NN + 1) * HID * sizeof(unsigned short));
    unsigned short* hA   = (unsigned short*)alloc((size_t)(NN + 1) * HID * sizeof(unsigned short));
    float* gsum    = (float*)alloc(NG * HID * sizeof(float));
    float* gcnt    = (float*)alloc(NG * sizeof(float));
    (void)ws_size; (void)in_sizes; (void)n_in; (void)out_size;

    // u8 partial [NSL][NN] (3.2 MB) aliases tbuf rows 0..NN-1 (6.4 MB) — dead
    // until CSR done; zero pad-rows (written by k_init) are beyond the alias.
    unsigned char* partial = (unsigned char*)tbuf;
    unsigned short* tzero = tbuf + (size_t)NN * HID;
    unsigned short* hzero = hA + (size_t)NN * HID;

    // ---- CSR build: zero per-edge global atomics; rows padded to 16 ----
    k_init<<<17, 256, 0, stream>>>(gsum, gcnt, tzero, hzero);
    k_hist3<<<CSRGRID, CSR_T, 0, stream>>>(edst, partial);
    k_scanA<<<NB, SCAN_B, 0, stream>>>(partial, row_ptr, bsum, dinv, deg);
    k_scanB<<<1, 128, 0, stream>>>(bsum);
    k_scanC<<<NB, SCAN_B, 0, stream>>>(row_ptr, bsum, deg, csr_src);
    k_scat3<<<CSRGRID, CSR_T, 0, stream>>>(esrc, edst, row_ptr, partial, csr_src);

    // ---- layer 0 GEMM (MFMA) -> t0 ----
    k_gemm0<<<G0_GRID, 256, 0, stream>>>(x, W0, dinv, tbuf);
    // ---- agg0 fused with layer-1 GEMM (MFMA epilogue): t0 -> t1 (hA) ----
    k_aggf<<<AGF_GRID, 512, 0, stream>>>(tbuf, row_ptr, csr_src, dinv, b0, W1, hA);
    // ---- agg1 fused with layer-2 GEMM (MFMA epilogue): t1 -> t2 (tbuf) ----
    k_aggf<<<AGF_GRID, 512, 0, stream>>>(hA, row_ptr, csr_src, dinv, b1, W2, tbuf);
    // ---- agg2 (final): t2 -> h3 (hA) ----
    k_agga<<<AGG_GRID, 256, 0, stream>>>(tbuf, row_ptr, csr_src, dinv, b2, hA);

    // ---- pooling + classifier ----
    k_pool2<<<POOL_GRID, 256, 0, stream>>>(hA, batch, gsum, gcnt);
    k_classify<<<1, 128, 0, stream>>>(gsum, gcnt, Wl, bl, out);
}

// Round 17
// 211.804 us; speedup vs baseline: 1.0056x; 1.0056x over previous
//
#include <hip/hip_runtime.h>
#include <hip/hip_bf16.h>

#define NN 100000
#define NE 1600000
#define NG 128
#define FIN 128
#define HID 32
#define NCLS 10

#define EG4 (NE / 4)           // 400000 int4 edge groups

// atomic-free CSR build
#define NSL 32                 // edge-list slices
#define GPS (EG4 / NSL)        // 12500 int4 groups per slice
#define RS 8                   // node sub-ranges (bid&7 -> XCD-local csr writes)
#define SUBN (NN / RS)         // 12500 nodes per range -> 50KB LDS counters
#define CSRGRID (RS * NSL)     // 256 blocks
#define CSR_T 1024             // 16 waves/CU -> latency hiding

#define PAD 16                 // CSR rows padded to multiple of 16 (zero-row idx NN)
#define NEP (NE + NN * PAD + 64)   // padded csr capacity + prefetch slack

#define SCAN_B 1024
#define NB ((NN + SCAN_B - 1) / SCAN_B)      // 98

#define POOL_CHUNK 512
#define POOL_SEG 16
#define POOL_GSPAN 32
#define POOL_GRID ((NN + POOL_CHUNK - 1) / POOL_CHUNK)

// GEMM0 MFMA tiling
#define G0_NODES 64
#define G0_GRID ((NN + G0_NODES - 1) / G0_NODES)
#define XPAD 136

// agg grids
#define AGG_GRID (NN / 4)      // final agg: 25000 blocks x 4 waves (1 node/wave)
#define AGF_GRID (NN / 16)     // fused agg: 6250 blocks x 16 waves (16 nodes)

typedef int int4v __attribute__((ext_vector_type(4)));
typedef __attribute__((ext_vector_type(8))) short short8;
typedef __attribute__((ext_vector_type(4))) float f32x4;

__device__ inline unsigned short f2bf(float f) {
    unsigned int u = __float_as_uint(f);
    unsigned int r = u + 0x7FFFu + ((u >> 16) & 1u);   // RNE
    return (unsigned short)(r >> 16);
}
__device__ inline float bf2f(unsigned short v) {
    return __uint_as_float(((unsigned int)v) << 16);
}

// ---------------- init: zero pooling accumulators + zero pad-rows ----------------
__global__ void k_init(float* __restrict__ gsum, float* __restrict__ gcnt,
                       unsigned short* __restrict__ tzero,
                       unsigned short* __restrict__ hzero) {
    int i = blockIdx.x * blockDim.x + threadIdx.x;
    if (i < NG * HID) gsum[i] = 0.f;
    if (i < NG) gcnt[i] = 0.f;
    if (i < HID) { tzero[i] = 0; hzero[i] = 0; }   // row NN of both gather buffers
}

// ------- hist: LDS count per node-range per slice; u8 partial store. -------
__global__ __launch_bounds__(CSR_T) void k_hist3(const int* __restrict__ dst,
                                                 unsigned char* __restrict__ partial) {
    const int r = blockIdx.x & (RS - 1);
    const int s = blockIdx.x >> 3;
    const int node0 = r * SUBN;
    __shared__ int lcnt[SUBN];                 // 50 KB
    for (int k = threadIdx.x; k < SUBN; k += CSR_T) lcnt[k] = 0;
    __syncthreads();
    const int g1 = (s + 1) * GPS;
    for (int g = s * GPS + threadIdx.x; g < g1; g += CSR_T) {
        const int4v d = *((const int4v*)dst + g);
        unsigned k;
        k = (unsigned)(d.x - node0); if (k < SUBN) atomicAdd(&lcnt[k], 1);
        k = (unsigned)(d.y - node0); if (k < SUBN) atomicAdd(&lcnt[k], 1);
        k = (unsigned)(d.z - node0); if (k < SUBN) atomicAdd(&lcnt[k], 1);
        k = (unsigned)(d.w - node0); if (k < SUBN) atomicAdd(&lcnt[k], 1);
    }
    __syncthreads();
    for (int k = threadIdx.x; k < SUBN; k += CSR_T)
        partial[s * NN + node0 + k] = (unsigned char)lcnt[k];
}

// ------- scanA: fold NSL u8 partials/node -> deg (+ in-place exclusive prefix
//         over slices), dinv, deg[], block-exclusive scan of PADDED degrees -------
__global__ void k_scanA(unsigned char* __restrict__ partial, int* __restrict__ row_ptr,
                        int* __restrict__ bsum, float* __restrict__ dinv,
                        int* __restrict__ deg) {
    __shared__ int lds[SCAN_B];
    int i = blockIdx.x * SCAN_B + threadIdx.x;
    int pv = 0;
    if (i < NN) {
        int run = 0;
#pragma unroll
        for (int s = 0; s < NSL; s++) {
            int c = partial[s * NN + i];
            partial[s * NN + i] = (unsigned char)run;   // exclusive prefix (<= deg <= 255)
            run += c;
        }
        deg[i] = run;
        dinv[i] = rsqrtf((float)run + 1.0f);
        pv = (run + PAD - 1) & ~(PAD - 1);              // padded degree
    }
    lds[threadIdx.x] = pv;
    __syncthreads();
    int val = pv;
    for (int off = 1; off < SCAN_B; off <<= 1) {
        int u = 0;
        if ((int)threadIdx.x >= off) u = lds[threadIdx.x - off];
        __syncthreads();
        if ((int)threadIdx.x >= off) { val += u; lds[threadIdx.x] = val; }
        __syncthreads();
    }
    if (i < NN) row_ptr[i] = val - pv;
    if (threadIdx.x == SCAN_B - 1) bsum[blockIdx.x] = val;
}

// ---------------- scanB: scan block sums ----------------
__global__ void k_scanB(int* __restrict__ bsum) {
    __shared__ int lds[128];
    int t = threadIdx.x;
    int v = (t < NB) ? bsum[t] : 0;
    lds[t] = v;
    __syncthreads();
    int val = v;
    for (int off = 1; off < 128; off <<= 1) {
        int u = 0;
        if (t >= off) u = lds[t - off];
        __syncthreads();
        if (t >= off) { val += u; lds[t] = val; }
        __syncthreads();
    }
    if (t < NB) bsum[t] = val - v;
}

// ------- scanC: add block offsets; fix row_ptr[NN]; fill pad slots (fused k_pad) ----
__global__ void k_scanC(int* __restrict__ row_ptr, const int* __restrict__ bsum,
                        const int* __restrict__ deg, int* __restrict__ csr_src) {
    int i = blockIdx.x * SCAN_B + threadIdx.x;
    if (i < NN) {
        int r = row_ptr[i] + bsum[blockIdx.x];
        row_ptr[i] = r;
        int d = deg[i];
        int pd = (d + PAD - 1) & ~(PAD - 1);
        if (i == NN - 1) row_ptr[NN] = r + pd;
        for (int j = r + d; j < r + pd; j++) csr_src[j] = NN;   // pad -> zero row
    }
}

// ------- scatter: LDS cursor = row_ptr + u8 slice-prefix; LDS atomics only -------
__global__ __launch_bounds__(CSR_T) void k_scat3(const int* __restrict__ src,
                                                 const int* __restrict__ dst,
                                                 const int* __restrict__ row_ptr,
                                                 const unsigned char* __restrict__ pref,
                                                 int* __restrict__ csr_src) {
    const int r = blockIdx.x & (RS - 1);
    const int s = blockIdx.x >> 3;
    const int node0 = r * SUBN;
    __shared__ int lcur[SUBN];                 // 50 KB
    for (int k = threadIdx.x; k < SUBN; k += CSR_T)
        lcur[k] = row_ptr[node0 + k] + (int)pref[s * NN + node0 + k];
    __syncthreads();
    const int g1 = (s + 1) * GPS;
    for (int g = s * GPS + threadIdx.x; g < g1; g += CSR_T) {
        const int4v d = *((const int4v*)dst + g);
        const int4v sx = *((const int4v*)src + g);
        unsigned k;
        k = (unsigned)(d.x - node0); if (k < SUBN) { int p = atomicAdd(&lcur[k], 1); csr_src[p] = sx.x; }
        k = (unsigned)(d.y - node0); if (k < SUBN) { int p = atomicAdd(&lcur[k], 1); csr_src[p] = sx.y; }
        k = (unsigned)(d.z - node0); if (k < SUBN) { int p = atomicAdd(&lcur[k], 1); csr_src[p] = sx.z; }
        k = (unsigned)(d.w - node0); if (k < SUBN) { int p = atomicAdd(&lcur[k], 1); csr_src[p] = sx.w; }
    }
}

// ---------------- layer-0 GEMM via bf16 MFMA: t = bf16((x @ W0) * dinv) --------
__global__ void k_gemm0(const float* __restrict__ x, const float* __restrict__ W,
                        const float* __restrict__ dinv, unsigned short* __restrict__ t) {
    __shared__ __align__(16) unsigned short x_lds[G0_NODES][XPAD];
    __shared__ __align__(16) unsigned short wt_lds[HID][XPAD];
    const int tid = threadIdx.x;
    const int node0 = blockIdx.x * G0_NODES;

#pragma unroll
    for (int r = 0; r < 8; r++) {
        int q = tid + 256 * r;
        int row = q >> 5;
        int c4 = q & 31;
        float4 xv = {0.f, 0.f, 0.f, 0.f};
        int node = node0 + row;
        if (node < NN) xv = ((const float4*)(x + (size_t)node * FIN))[c4];
        ushort4 b;
        b.x = f2bf(xv.x); b.y = f2bf(xv.y); b.z = f2bf(xv.z); b.w = f2bf(xv.w);
        *(ushort4*)&x_lds[row][c4 * 4] = b;
    }
#pragma unroll
    for (int r = 0; r < 16; r++) {
        int q = tid + 256 * r;
        int k = q >> 5, n = q & 31;
        wt_lds[n][k] = f2bf(W[q]);
    }
    __syncthreads();

    const int w = tid >> 6;
    const int lane = tid & 63;
    const int row = lane & 15;
    const int kg = lane >> 4;
    const int w16 = w * 16;

    f32x4 acc0 = {0.f, 0.f, 0.f, 0.f};
    f32x4 acc1 = {0.f, 0.f, 0.f, 0.f};
#pragma unroll
    for (int s = 0; s < 4; s++) {
        short8 a  = *(const short8*)&x_lds[w16 + row][s * 32 + kg * 8];
        short8 b0 = *(const short8*)&wt_lds[row][s * 32 + kg * 8];
        short8 b1 = *(const short8*)&wt_lds[16 + row][s * 32 + kg * 8];
        acc0 = __builtin_amdgcn_mfma_f32_16x16x32_bf16(a, b0, acc0, 0, 0, 0);
        acc1 = __builtin_amdgcn_mfma_f32_16x16x32_bf16(a, b1, acc1, 0, 0, 0);
    }

    const int f = lane & 15;
#pragma unroll
    for (int j = 0; j < 4; j++) {
        int node = node0 + w16 + kg * 4 + j;
        if (node < NN) {
            float di = dinv[node];
            t[(size_t)node * HID + f]      = f2bf(acc0[j] * di);
            t[(size_t)node * HID + 16 + f] = f2bf(acc1[j] * di);
        }
    }
}

// ------- fused agg (round-14 structure + conflict-free wt staging):
//         1024 thr = 16 waves = 16 nodes; 1-deep loop with idx prefetch;
//         h tile -> LDS -> wave 0: t' = bf16((h @ Wn) * dinv), 2 MFMAs. -------
__global__ __launch_bounds__(1024, 8) void k_aggf(const unsigned short* __restrict__ t,
                                                  const int* __restrict__ row_ptr,
                                                  const int* __restrict__ csr_src,
                                                  const float* __restrict__ dinv,
                                                  const float* __restrict__ b,
                                                  const float* __restrict__ Wn,
                                                  unsigned short* __restrict__ hout) {
    __shared__ __align__(16) unsigned short wt[HID][HID];   // W^T: wt[n][k], 2KB
    __shared__ __align__(16) unsigned hlds[16 * 16];        // 16 nodes x 32 bf16, 1KB
    {   // stage W transposed, conflict-free: consecutive threads -> consecutive k
        int q = threadIdx.x;                  // 1024 threads, 1024 elems
        int n = q >> 5, k = q & 31;
        wt[n][k] = f2bf(Wn[k * HID + n]);     // W row k, col n (L2-hot broadcast)
    }
    const int wave = threadIdx.x >> 6;
    const int wid = blockIdx.x * 16 + wave;            // node = wave id
    const int lane = threadIdx.x & 63;
    const int fp = lane & 15;                          // feature pair
    const int sub = lane >> 4;                         // edge subset 0..3
    const int beg = row_ptr[wid], end = row_ptr[wid + 1];
    const unsigned* twp = (const unsigned*)t;

    float accLo = 0.f, accHi = 0.f;
    if (sub == 0) {                                    // self term
        unsigned u = twp[(size_t)wid * 16 + fp];
        accLo = __uint_as_float(u << 16);
        accHi = __uint_as_float(u & 0xFFFF0000u);
    }
    int e = beg;
    int4v ia;
    if (e < end) ia = *(const int4v*)(csr_src + e + sub * 4);
    while (e < end) {
        const int4v ca = ia;
        const int en = e + 16;
        if (en < end) ia = *(const int4v*)(csr_src + en + sub * 4);
        unsigned u0 = twp[(size_t)ca.x * 16 + fp];
        unsigned u1 = twp[(size_t)ca.y * 16 + fp];
        unsigned u2 = twp[(size_t)ca.z * 16 + fp];
        unsigned u3 = twp[(size_t)ca.w * 16 + fp];
        accLo += __uint_as_float(u0 << 16);
        accHi += __uint_as_float(u0 & 0xFFFF0000u);
        accLo += __uint_as_float(u1 << 16);
        accHi += __uint_as_float(u1 & 0xFFFF0000u);
        accLo += __uint_as_float(u2 << 16);
        accHi += __uint_as_float(u2 & 0xFFFF0000u);
        accLo += __uint_as_float(u3 << 16);
        accHi += __uint_as_float(u3 & 0xFFFF0000u);
        e = en;
    }
    accLo += __shfl_xor(accLo, 16, 64);
    accHi += __shfl_xor(accHi, 16, 64);
    accLo += __shfl_xor(accLo, 32, 64);
    accHi += __shfl_xor(accHi, 32, 64);

    if (lane < 16) {                                   // h (post relu+bias) -> LDS tile
        const float di = dinv[wid];
        float hLo = fmaxf(fmaf(accLo, di, b[2 * fp]), 0.f);
        float hHi = fmaxf(fmaf(accHi, di, b[2 * fp + 1]), 0.f);
        hlds[wave * 16 + fp] = (unsigned)f2bf(hLo) | ((unsigned)f2bf(hHi) << 16);
    }
    __syncthreads();
    if (threadIdx.x >= 64) return;                     // wave 0 does the block GEMM

    const int row = lane & 15;                         // A-row (node) / D-col (feature)
    const int kg = lane >> 4;
    short8 a  = *(const short8*)((const unsigned short*)hlds + row * 32 + kg * 8);
    short8 b0 = *(const short8*)&wt[row][kg * 8];
    short8 b1 = *(const short8*)&wt[16 + row][kg * 8];
    f32x4 d0 = {0.f, 0.f, 0.f, 0.f};
    f32x4 d1 = {0.f, 0.f, 0.f, 0.f};
    d0 = __builtin_amdgcn_mfma_f32_16x16x32_bf16(a, b0, d0, 0, 0, 0);
    d1 = __builtin_amdgcn_mfma_f32_16x16x32_bf16(a, b1, d1, 0, 0, 0);
    const int node0 = blockIdx.x * 16;
#pragma unroll
    for (int j = 0; j < 4; j++) {
        int node = node0 + kg * 4 + j;
        float dv = dinv[node];
        hout[(size_t)node * HID + row]      = f2bf(d0[j] * dv);
        hout[(size_t)node * HID + 16 + row] = f2bf(d1[j] * dv);
    }
}

// ------- final agg (no fuse): one node/wave; 1-deep loop with idx prefetch. ----
__global__ __launch_bounds__(256, 8) void k_agga(const unsigned short* __restrict__ t,
                                                 const int* __restrict__ row_ptr,
                                                 const int* __restrict__ csr_src,
                                                 const float* __restrict__ dinv,
                                                 const float* __restrict__ b,
                                                 unsigned short* __restrict__ hout) {
    const int wid = (blockIdx.x * 256 + threadIdx.x) >> 6;
    if (wid >= NN) return;
    const int lane = threadIdx.x & 63;
    const int fp = lane & 15;
    const int sub = lane >> 4;
    const int beg = row_ptr[wid], end = row_ptr[wid + 1];
    const unsigned* tw = (const unsigned*)t;

    float accLo = 0.f, accHi = 0.f;
    if (sub == 0) {
        unsigned u = tw[(size_t)wid * 16 + fp];
        accLo = __uint_as_float(u << 16);
        accHi = __uint_as_float(u & 0xFFFF0000u);
    }
    int e = beg;
    int4v ia;
    if (e < end) ia = *(const int4v*)(csr_src + e + sub * 4);
    while (e < end) {
        const int4v ca = ia;
        const int en = e + 16;
        if (en < end) ia = *(const int4v*)(csr_src + en + sub * 4);
        unsigned u0 = tw[(size_t)ca.x * 16 + fp];
        unsigned u1 = tw[(size_t)ca.y * 16 + fp];
        unsigned u2 = tw[(size_t)ca.z * 16 + fp];
        unsigned u3 = tw[(size_t)ca.w * 16 + fp];
        accLo += __uint_as_float(u0 << 16);
        accHi += __uint_as_float(u0 & 0xFFFF0000u);
        accLo += __uint_as_float(u1 << 16);
        accHi += __uint_as_float(u1 & 0xFFFF0000u);
        accLo += __uint_as_float(u2 << 16);
        accHi += __uint_as_float(u2 & 0xFFFF0000u);
        accLo += __uint_as_float(u3 << 16);
        accHi += __uint_as_float(u3 & 0xFFFF0000u);
        e = en;
    }
    accLo += __shfl_xor(accLo, 16, 64);
    accHi += __shfl_xor(accHi, 16, 64);
    accLo += __shfl_xor(accLo, 32, 64);
    accHi += __shfl_xor(accHi, 32, 64);
    if (sub == 0) {
        float di = dinv[wid];
        float rLo = fmaxf(fmaf(accLo, di, b[2 * fp]), 0.f);
        float rHi = fmaxf(fmaf(accHi, di, b[2 * fp + 1]), 0.f);
        unsigned out = (unsigned)f2bf(rLo) | ((unsigned)f2bf(rHi) << 16);
        ((unsigned*)hout)[(size_t)wid * 16 + fp] = out;
    }
}

// ---------------- pooling (bf16 in): register-segment accumulate -> LDS bins ----
__global__ void k_pool2(const unsigned short* __restrict__ h, const int* __restrict__ batch,
                        float* __restrict__ gsum, float* __restrict__ gcnt) {
    __shared__ float lacc[POOL_GSPAN][HID];
    __shared__ float lcnt[POOL_GSPAN];
    __shared__ int s_gmin;
    const int chunk_start = blockIdx.x * POOL_CHUNK;

    for (int j = threadIdx.x; j < POOL_GSPAN * HID; j += 256) ((float*)lacc)[j] = 0.f;
    if (threadIdx.x < POOL_GSPAN) lcnt[threadIdx.x] = 0.f;
    if (threadIdx.x == 0) {
        int cs = chunk_start < NN ? chunk_start : NN - 1;
        s_gmin = batch[cs];
    }
    __syncthreads();
    const int gmin = s_gmin;

    const int seg = threadIdx.x >> 3;
    const int l = (threadIdx.x & 7) * 4;
    const int i0 = chunk_start + seg * POOL_SEG;

    float4 acc = {0.f, 0.f, 0.f, 0.f};
    float cnt = 0.f;
    int cur_g = -1;

    for (int k = 0; k < POOL_SEG; k++) {
        int i = i0 + k;
        if (i >= NN) break;
        int g = batch[i];
        if (g != cur_g) {
            if (cur_g >= 0) {
                int bin = cur_g - gmin;
                if (bin >= 0 && bin < POOL_GSPAN) {
                    atomicAdd(&lacc[bin][l + 0], acc.x);
                    atomicAdd(&lacc[bin][l + 1], acc.y);
                    atomicAdd(&lacc[bin][l + 2], acc.z);
                    atomicAdd(&lacc[bin][l + 3], acc.w);
                    if (l == 0) atomicAdd(&lcnt[bin], cnt);
                } else {
                    atomicAdd(&gsum[cur_g * HID + l + 0], acc.x);
                    atomicAdd(&gsum[cur_g * HID + l + 1], acc.y);
                    atomicAdd(&gsum[cur_g * HID + l + 2], acc.z);
                    atomicAdd(&gsum[cur_g * HID + l + 3], acc.w);
                    if (l == 0) atomicAdd(&gcnt[cur_g], cnt);
                }
            }
            cur_g = g;
            acc.x = acc.y = acc.z = acc.w = 0.f;
            cnt = 0.f;
        }
        const ushort4 v = *(const ushort4*)&h[(size_t)i * HID + l];
        acc.x += bf2f(v.x); acc.y += bf2f(v.y);
        acc.z += bf2f(v.z); acc.w += bf2f(v.w);
        cnt += 1.f;
    }
    if (cur_g >= 0) {
        int bin = cur_g - gmin;
        if (bin >= 0 && bin < POOL_GSPAN) {
            atomicAdd(&lacc[bin][l + 0], acc.x);
            atomicAdd(&lacc[bin][l + 1], acc.y);
            atomicAdd(&lacc[bin][l + 2], acc.z);
            atomicAdd(&lacc[bin][l + 3], acc.w);
            if (l == 0) atomicAdd(&lcnt[bin], cnt);
        } else {
            atomicAdd(&gsum[cur_g * HID + l + 0], acc.x);
            atomicAdd(&gsum[cur_g * HID + l + 1], acc.y);
            atomicAdd(&gsum[cur_g * HID + l + 2], acc.z);
            atomicAdd(&gsum[cur_g * HID + l + 3], acc.w);
            if (l == 0) atomicAdd(&gcnt[cur_g], cnt);
        }
    }
    __syncthreads();

    for (int j = threadIdx.x; j < POOL_GSPAN * HID; j += 256) {
        int bin = j / HID, f = j % HID;
        int g = gmin + bin;
        float v = lacc[bin][f];
        if (g < NG && v != 0.f) atomicAdd(&gsum[g * HID + f], v);
    }
    if (threadIdx.x < POOL_GSPAN) {
        int g = gmin + threadIdx.x;
        float c = lcnt[threadIdx.x];
        if (g < NG && c != 0.f) atomicAdd(&gcnt[g], c);
    }
}

// ---------------- classifier + log_softmax ----------------
__global__ void k_classify(const float* __restrict__ gsum, const float* __restrict__ gcnt,
                           const float* __restrict__ Wl, const float* __restrict__ bl,
                           float* __restrict__ out) {
    __shared__ float w[HID * NCLS];
    __shared__ float bb[NCLS];
    int t = threadIdx.x;
    for (int j = t; j < HID * NCLS; j += blockDim.x) w[j] = Wl[j];
    if (t < NCLS) bb[t] = bl[t];
    __syncthreads();
    if (t >= NG) return;
    float c = gcnt[t];
    c = c > 1.f ? c : 1.f;
    float p[HID];
#pragma unroll
    for (int k = 0; k < HID; k++) p[k] = gsum[t * HID + k] / c;
    float lg[NCLS];
    float m = -1e30f;
#pragma unroll
    for (int c2 = 0; c2 < NCLS; c2++) {
        float a = bb[c2];
#pragma unroll
        for (int k = 0; k < HID; k++) a = fmaf(p[k], w[k * NCLS + c2], a);
        a = a > 0.f ? a : 0.f;
        lg[c2] = a;
        m = fmaxf(m, a);
    }
    float s = 0.f;
#pragma unroll
    for (int c2 = 0; c2 < NCLS; c2++) s += expf(lg[c2] - m);
    float ls = logf(s);
#pragma unroll
    for (int c2 = 0; c2 < NCLS; c2++) out[t * NCLS + c2] = lg[c2] - m - ls;
}

extern "C" void kernel_launch(void* const* d_in, const int* in_sizes, int n_in,
                              void* d_out, int out_size, void* d_ws, size_t ws_size,
                              hipStream_t stream) {
    const float* x  = (const float*)d_in[0];
    const int* ei   = (const int*)d_in[1];
    const int* batch = (const int*)d_in[2];
    const float* W0 = (const float*)d_in[3];
    const float* b0 = (const float*)d_in[4];
    const float* W1 = (const float*)d_in[5];
    const float* b1 = (const float*)d_in[6];
    const float* W2 = (const float*)d_in[7];
    const float* b2 = (const float*)d_in[8];
    const float* Wl = (const float*)d_in[9];
    const float* bl = (const float*)d_in[10];
    float* out = (float*)d_out;

    const int* esrc = ei;
    const int* edst = ei + NE;

    char* ws = (char*)d_ws;
    size_t off = 0;
    auto alloc = [&](size_t bytes) -> void* {
        void* p = ws + off;
        off = (off + bytes + 511) & ~(size_t)511;
        return p;
    };
    int*   row_ptr = (int*)alloc((NN + 1) * sizeof(int));
    float* dinv    = (float*)alloc(NN * sizeof(float));
    int*   deg     = (int*)alloc(NN * sizeof(int));
    int*   bsum    = (int*)alloc(256 * sizeof(int));
    int*   csr_src = (int*)alloc((size_t)NEP * sizeof(int));
    unsigned short* tbuf = (unsigned short*)alloc((size_t)(NN + 1) * HID * sizeof(unsigned short));
    unsigned short* hA   = (unsigned short*)alloc((size_t)(NN + 1) * HID * sizeof(unsigned short));
    float* gsum    = (float*)alloc(NG * HID * sizeof(float));
    float* gcnt    = (float*)alloc(NG * sizeof(float));
    (void)ws_size; (void)in_sizes; (void)n_in; (void)out_size;

    // u8 partial [NSL][NN] (3.2 MB) aliases tbuf rows 0..NN-1 (6.4 MB) — dead
    // until CSR done; zero pad-rows (written by k_init) are beyond the alias.
    unsigned char* partial = (unsigned char*)tbuf;
    unsigned short* tzero = tbuf + (size_t)NN * HID;
    unsigned short* hzero = hA + (size_t)NN * HID;

    // ---- CSR build: zero per-edge global atomics; rows padded to 16 ----
    k_init<<<17, 256, 0, stream>>>(gsum, gcnt, tzero, hzero);
    k_hist3<<<CSRGRID, CSR_T, 0, stream>>>(edst, partial);
    k_scanA<<<NB, SCAN_B, 0, stream>>>(partial, row_ptr, bsum, dinv, deg);
    k_scanB<<<1, 128, 0, stream>>>(bsum);
    k_scanC<<<NB, SCAN_B, 0, stream>>>(row_ptr, bsum, deg, csr_src);
    k_scat3<<<CSRGRID, CSR_T, 0, stream>>>(esrc, edst, row_ptr, partial, csr_src);

    // ---- layer 0 GEMM (MFMA) -> t0 ----
    k_gemm0<<<G0_GRID, 256, 0, stream>>>(x, W0, dinv, tbuf);
    // ---- agg0 fused with layer-1 GEMM (MFMA epilogue): t0 -> t1 (hA) ----
    k_aggf<<<AGF_GRID, 1024, 0, stream>>>(tbuf, row_ptr, csr_src, dinv, b0, W1, hA);
    // ---- agg1 fused with layer-2 GEMM (MFMA epilogue): t1 -> t2 (tbuf) ----
    k_aggf<<<AGF_GRID, 1024, 0, stream>>>(hA, row_ptr, csr_src, dinv, b1, W2, tbuf);
    // ---- agg2 (final): t2 -> h3 (hA) ----
    k_agga<<<AGG_GRID, 256, 0, stream>>>(tbuf, row_ptr, csr_src, dinv, b2, hA);

    // ---- pooling + classifier ----
    k_pool2<<<POOL_GRID, 256, 0, stream>>>(hA, batch, gsum, gcnt);
    k_classify<<<1, 128, 0, stream>>>(gsum, gcnt, Wl, bl, out);
}

// Round 18
// 198.221 us; speedup vs baseline: 1.0745x; 1.0685x over previous
//
#include <hip/hip_runtime.h>
#include <hip/hip_bf16.h>

#define NN 100000
#define NE 1600000
#define NG 128
#define FIN 128
#define HID 32
#define NCLS 10

#define EG4 (NE / 4)           // 400000 int4 edge groups

// atomic-free CSR build
#define NSL 32                 // edge-list slices
#define GPS (EG4 / NSL)        // 12500 int4 groups per slice
#define RS 8                   // node sub-ranges (bid&7 -> XCD-local csr writes)
#define SUBN (NN / RS)         // 12500 nodes per range -> 50KB LDS counters
#define CSRGRID (RS * NSL)     // 256 blocks
#define CSR_T 1024             // 16 waves/CU -> latency hiding

#define PAD 16                 // CSR rows padded to multiple of 16 (zero-row idx NN)
#define NEP (NE + NN * PAD + 64)   // padded csr capacity + prefetch slack

#define SCAN_B 1024
#define NB ((NN + SCAN_B - 1) / SCAN_B)      // 98

#define POOL_CHUNK 512
#define POOL_SEG 16
#define POOL_GSPAN 32
#define POOL_GRID ((NN + POOL_CHUNK - 1) / POOL_CHUNK)

// GEMM0 MFMA tiling
#define G0_NODES 64
#define G0_GRID ((NN + G0_NODES - 1) / G0_NODES)
#define XPAD 136

// agg grids
#define AGG_GRID (NN / 4)      // final agg: 25000 blocks x 4 waves (1 node/wave)
#define AGF_GRID (NN / 16)     // fused agg: 6250 blocks x 16 waves (16 nodes)

#define WPAD 40                // wt second dim: 32 + 8 pad (kills 16-way write conflict)

typedef int int4v __attribute__((ext_vector_type(4)));
typedef __attribute__((ext_vector_type(8))) short short8;
typedef __attribute__((ext_vector_type(4))) float f32x4;

__device__ inline unsigned short f2bf(float f) {
    unsigned int u = __float_as_uint(f);
    unsigned int r = u + 0x7FFFu + ((u >> 16) & 1u);   // RNE
    return (unsigned short)(r >> 16);
}
__device__ inline float bf2f(unsigned short v) {
    return __uint_as_float(((unsigned int)v) << 16);
}

// ---------------- init: zero pooling accumulators + zero pad-rows ----------------
__global__ void k_init(float* __restrict__ gsum, float* __restrict__ gcnt,
                       unsigned short* __restrict__ tzero,
                       unsigned short* __restrict__ hzero) {
    int i = blockIdx.x * blockDim.x + threadIdx.x;
    if (i < NG * HID) gsum[i] = 0.f;
    if (i < NG) gcnt[i] = 0.f;
    if (i < HID) { tzero[i] = 0; hzero[i] = 0; }   // row NN of both gather buffers
}

// ------- hist: LDS count per node-range per slice; u8 partial store. -------
__global__ __launch_bounds__(CSR_T) void k_hist3(const int* __restrict__ dst,
                                                 unsigned char* __restrict__ partial) {
    const int r = blockIdx.x & (RS - 1);
    const int s = blockIdx.x >> 3;
    const int node0 = r * SUBN;
    __shared__ int lcnt[SUBN];                 // 50 KB
    for (int k = threadIdx.x; k < SUBN; k += CSR_T) lcnt[k] = 0;
    __syncthreads();
    const int g1 = (s + 1) * GPS;
    for (int g = s * GPS + threadIdx.x; g < g1; g += CSR_T) {
        const int4v d = *((const int4v*)dst + g);
        unsigned k;
        k = (unsigned)(d.x - node0); if (k < SUBN) atomicAdd(&lcnt[k], 1);
        k = (unsigned)(d.y - node0); if (k < SUBN) atomicAdd(&lcnt[k], 1);
        k = (unsigned)(d.z - node0); if (k < SUBN) atomicAdd(&lcnt[k], 1);
        k = (unsigned)(d.w - node0); if (k < SUBN) atomicAdd(&lcnt[k], 1);
    }
    __syncthreads();
    for (int k = threadIdx.x; k < SUBN; k += CSR_T)
        partial[s * NN + node0 + k] = (unsigned char)lcnt[k];
}

// ------- scanA: fold NSL u8 partials/node -> deg (+ in-place exclusive prefix
//         over slices), dinv, deg[], block-exclusive scan of PADDED degrees -------
__global__ void k_scanA(unsigned char* __restrict__ partial, int* __restrict__ row_ptr,
                        int* __restrict__ bsum, float* __restrict__ dinv,
                        int* __restrict__ deg) {
    __shared__ int lds[SCAN_B];
    int i = blockIdx.x * SCAN_B + threadIdx.x;
    int pv = 0;
    if (i < NN) {
        int run = 0;
#pragma unroll
        for (int s = 0; s < NSL; s++) {
            int c = partial[s * NN + i];
            partial[s * NN + i] = (unsigned char)run;   // exclusive prefix (<= deg <= 255)
            run += c;
        }
        deg[i] = run;
        dinv[i] = rsqrtf((float)run + 1.0f);
        pv = (run + PAD - 1) & ~(PAD - 1);              // padded degree
    }
    lds[threadIdx.x] = pv;
    __syncthreads();
    int val = pv;
    for (int off = 1; off < SCAN_B; off <<= 1) {
        int u = 0;
        if ((int)threadIdx.x >= off) u = lds[threadIdx.x - off];
        __syncthreads();
        if ((int)threadIdx.x >= off) { val += u; lds[threadIdx.x] = val; }
        __syncthreads();
    }
    if (i < NN) row_ptr[i] = val - pv;
    if (threadIdx.x == SCAN_B - 1) bsum[blockIdx.x] = val;
}

// ---------------- scanB: scan block sums ----------------
__global__ void k_scanB(int* __restrict__ bsum) {
    __shared__ int lds[128];
    int t = threadIdx.x;
    int v = (t < NB) ? bsum[t] : 0;
    lds[t] = v;
    __syncthreads();
    int val = v;
    for (int off = 1; off < 128; off <<= 1) {
        int u = 0;
        if (t >= off) u = lds[t - off];
        __syncthreads();
        if (t >= off) { val += u; lds[t] = val; }
        __syncthreads();
    }
    if (t < NB) bsum[t] = val - v;
}

// ------- scanC: add block offsets; fix row_ptr[NN]; fill pad slots (fused k_pad) ----
__global__ void k_scanC(int* __restrict__ row_ptr, const int* __restrict__ bsum,
                        const int* __restrict__ deg, int* __restrict__ csr_src) {
    int i = blockIdx.x * SCAN_B + threadIdx.x;
    if (i < NN) {
        int r = row_ptr[i] + bsum[blockIdx.x];
        row_ptr[i] = r;
        int d = deg[i];
        int pd = (d + PAD - 1) & ~(PAD - 1);
        if (i == NN - 1) row_ptr[NN] = r + pd;
        for (int j = r + d; j < r + pd; j++) csr_src[j] = NN;   // pad -> zero row
    }
}

// ------- scatter: LDS cursor = row_ptr + u8 slice-prefix; LDS atomics only -------
__global__ __launch_bounds__(CSR_T) void k_scat3(const int* __restrict__ src,
                                                 const int* __restrict__ dst,
                                                 const int* __restrict__ row_ptr,
                                                 const unsigned char* __restrict__ pref,
                                                 int* __restrict__ csr_src) {
    const int r = blockIdx.x & (RS - 1);
    const int s = blockIdx.x >> 3;
    const int node0 = r * SUBN;
    __shared__ int lcur[SUBN];                 // 50 KB
    for (int k = threadIdx.x; k < SUBN; k += CSR_T)
        lcur[k] = row_ptr[node0 + k] + (int)pref[s * NN + node0 + k];
    __syncthreads();
    const int g1 = (s + 1) * GPS;
    for (int g = s * GPS + threadIdx.x; g < g1; g += CSR_T) {
        const int4v d = *((const int4v*)dst + g);
        const int4v sx = *((const int4v*)src + g);
        unsigned k;
        k = (unsigned)(d.x - node0); if (k < SUBN) { int p = atomicAdd(&lcur[k], 1); csr_src[p] = sx.x; }
        k = (unsigned)(d.y - node0); if (k < SUBN) { int p = atomicAdd(&lcur[k], 1); csr_src[p] = sx.y; }
        k = (unsigned)(d.z - node0); if (k < SUBN) { int p = atomicAdd(&lcur[k], 1); csr_src[p] = sx.z; }
        k = (unsigned)(d.w - node0); if (k < SUBN) { int p = atomicAdd(&lcur[k], 1); csr_src[p] = sx.w; }
    }
}

// ---------------- layer-0 GEMM via bf16 MFMA: t = bf16((x @ W0) * dinv) --------
__global__ void k_gemm0(const float* __restrict__ x, const float* __restrict__ W,
                        const float* __restrict__ dinv, unsigned short* __restrict__ t) {
    __shared__ __align__(16) unsigned short x_lds[G0_NODES][XPAD];
    __shared__ __align__(16) unsigned short wt_lds[HID][XPAD];
    const int tid = threadIdx.x;
    const int node0 = blockIdx.x * G0_NODES;

#pragma unroll
    for (int r = 0; r < 8; r++) {
        int q = tid + 256 * r;
        int row = q >> 5;
        int c4 = q & 31;
        float4 xv = {0.f, 0.f, 0.f, 0.f};
        int node = node0 + row;
        if (node < NN) xv = ((const float4*)(x + (size_t)node * FIN))[c4];
        ushort4 b;
        b.x = f2bf(xv.x); b.y = f2bf(xv.y); b.z = f2bf(xv.z); b.w = f2bf(xv.w);
        *(ushort4*)&x_lds[row][c4 * 4] = b;
    }
#pragma unroll
    for (int r = 0; r < 16; r++) {
        int q = tid + 256 * r;
        int k = q >> 5, n = q & 31;
        wt_lds[n][k] = f2bf(W[q]);
    }
    __syncthreads();

    const int w = tid >> 6;
    const int lane = tid & 63;
    const int row = lane & 15;
    const int kg = lane >> 4;
    const int w16 = w * 16;

    f32x4 acc0 = {0.f, 0.f, 0.f, 0.f};
    f32x4 acc1 = {0.f, 0.f, 0.f, 0.f};
#pragma unroll
    for (int s = 0; s < 4; s++) {
        short8 a  = *(const short8*)&x_lds[w16 + row][s * 32 + kg * 8];
        short8 b0 = *(const short8*)&wt_lds[row][s * 32 + kg * 8];
        short8 b1 = *(const short8*)&wt_lds[16 + row][s * 32 + kg * 8];
        acc0 = __builtin_amdgcn_mfma_f32_16x16x32_bf16(a, b0, acc0, 0, 0, 0);
        acc1 = __builtin_amdgcn_mfma_f32_16x16x32_bf16(a, b1, acc1, 0, 0, 0);
    }

    const int f = lane & 15;
#pragma unroll
    for (int j = 0; j < 4; j++) {
        int node = node0 + w16 + kg * 4 + j;
        if (node < NN) {
            float di = dinv[node];
            t[(size_t)node * HID + f]      = f2bf(acc0[j] * di);
            t[(size_t)node * HID + 16 + f] = f2bf(acc1[j] * di);
        }
    }
}

// ------- fused agg (round-15 structure + padded wt): 1024 thr = 16 waves =
//         16 nodes; coalesced W staging (Wn[q]); wt row stride 40 shorts ->
//         staging write 4-way (free) instead of 16-way; 1-deep idx prefetch;
//         h tile -> LDS -> wave 0: t' = bf16((h @ Wn) * dinv), 2 MFMAs. -------
__global__ __launch_bounds__(1024, 8) void k_aggf(const unsigned short* __restrict__ t,
                                                  const int* __restrict__ row_ptr,
                                                  const int* __restrict__ csr_src,
                                                  const float* __restrict__ dinv,
                                                  const float* __restrict__ b,
                                                  const float* __restrict__ Wn,
                                                  unsigned short* __restrict__ hout) {
    __shared__ __align__(16) unsigned short wt[HID][WPAD];  // W^T padded, 2.5KB
    __shared__ __align__(16) unsigned hlds[16 * 16];        // 16 nodes x 32 bf16, 1KB
    {   // stage W transposed; global read coalesced (Wn[q] linear)
        int q = threadIdx.x;                  // 1024 threads, 1024 elems
        int k = q >> 5, n = q & 31;
        wt[n][k] = f2bf(Wn[q]);
    }
    const int wave = threadIdx.x >> 6;
    const int wid = blockIdx.x * 16 + wave;            // node = wave id
    const int lane = threadIdx.x & 63;
    const int fp = lane & 15;                          // feature pair
    const int sub = lane >> 4;                         // edge subset 0..3
    const int beg = row_ptr[wid], end = row_ptr[wid + 1];
    const unsigned* twp = (const unsigned*)t;

    float accLo = 0.f, accHi = 0.f;
    if (sub == 0) {                                    // self term
        unsigned u = twp[(size_t)wid * 16 + fp];
        accLo = __uint_as_float(u << 16);
        accHi = __uint_as_float(u & 0xFFFF0000u);
    }
    int e = beg;
    int4v ia;
    if (e < end) ia = *(const int4v*)(csr_src + e + sub * 4);
    while (e < end) {
        const int4v ca = ia;
        const int en = e + 16;
        if (en < end) ia = *(const int4v*)(csr_src + en + sub * 4);
        unsigned u0 = twp[(size_t)ca.x * 16 + fp];
        unsigned u1 = twp[(size_t)ca.y * 16 + fp];
        unsigned u2 = twp[(size_t)ca.z * 16 + fp];
        unsigned u3 = twp[(size_t)ca.w * 16 + fp];
        accLo += __uint_as_float(u0 << 16);
        accHi += __uint_as_float(u0 & 0xFFFF0000u);
        accLo += __uint_as_float(u1 << 16);
        accHi += __uint_as_float(u1 & 0xFFFF0000u);
        accLo += __uint_as_float(u2 << 16);
        accHi += __uint_as_float(u2 & 0xFFFF0000u);
        accLo += __uint_as_float(u3 << 16);
        accHi += __uint_as_float(u3 & 0xFFFF0000u);
        e = en;
    }
    accLo += __shfl_xor(accLo, 16, 64);
    accHi += __shfl_xor(accHi, 16, 64);
    accLo += __shfl_xor(accLo, 32, 64);
    accHi += __shfl_xor(accHi, 32, 64);

    if (lane < 16) {                                   // h (post relu+bias) -> LDS tile
        const float di = dinv[wid];
        float hLo = fmaxf(fmaf(accLo, di, b[2 * fp]), 0.f);
        float hHi = fmaxf(fmaf(accHi, di, b[2 * fp + 1]), 0.f);
        hlds[wave * 16 + fp] = (unsigned)f2bf(hLo) | ((unsigned)f2bf(hHi) << 16);
    }
    __syncthreads();
    if (threadIdx.x >= 64) return;                     // wave 0 does the block GEMM

    const int row = lane & 15;                         // A-row (node) / D-col (feature)
    const int kg = lane >> 4;
    short8 a  = *(const short8*)((const unsigned short*)hlds + row * 32 + kg * 8);
    short8 b0 = *(const short8*)&wt[row][kg * 8];
    short8 b1 = *(const short8*)&wt[16 + row][kg * 8];
    f32x4 d0 = {0.f, 0.f, 0.f, 0.f};
    f32x4 d1 = {0.f, 0.f, 0.f, 0.f};
    d0 = __builtin_amdgcn_mfma_f32_16x16x32_bf16(a, b0, d0, 0, 0, 0);
    d1 = __builtin_amdgcn_mfma_f32_16x16x32_bf16(a, b1, d1, 0, 0, 0);
    const int node0 = blockIdx.x * 16;
#pragma unroll
    for (int j = 0; j < 4; j++) {
        int node = node0 + kg * 4 + j;
        float dv = dinv[node];
        hout[(size_t)node * HID + row]      = f2bf(d0[j] * dv);
        hout[(size_t)node * HID + 16 + row] = f2bf(d1[j] * dv);
    }
}

// ------- final agg (no fuse): one node/wave; 1-deep loop with idx prefetch. ----
__global__ __launch_bounds__(256, 8) void k_agga(const unsigned short* __restrict__ t,
                                                 const int* __restrict__ row_ptr,
                                                 const int* __restrict__ csr_src,
                                                 const float* __restrict__ dinv,
                                                 const float* __restrict__ b,
                                                 unsigned short* __restrict__ hout) {
    const int wid = (blockIdx.x * 256 + threadIdx.x) >> 6;
    if (wid >= NN) return;
    const int lane = threadIdx.x & 63;
    const int fp = lane & 15;
    const int sub = lane >> 4;
    const int beg = row_ptr[wid], end = row_ptr[wid + 1];
    const unsigned* tw = (const unsigned*)t;

    float accLo = 0.f, accHi = 0.f;
    if (sub == 0) {
        unsigned u = tw[(size_t)wid * 16 + fp];
        accLo = __uint_as_float(u << 16);
        accHi = __uint_as_float(u & 0xFFFF0000u);
    }
    int e = beg;
    int4v ia;
    if (e < end) ia = *(const int4v*)(csr_src + e + sub * 4);
    while (e < end) {
        const int4v ca = ia;
        const int en = e + 16;
        if (en < end) ia = *(const int4v*)(csr_src + en + sub * 4);
        unsigned u0 = tw[(size_t)ca.x * 16 + fp];
        unsigned u1 = tw[(size_t)ca.y * 16 + fp];
        unsigned u2 = tw[(size_t)ca.z * 16 + fp];
        unsigned u3 = tw[(size_t)ca.w * 16 + fp];
        accLo += __uint_as_float(u0 << 16);
        accHi += __uint_as_float(u0 & 0xFFFF0000u);
        accLo += __uint_as_float(u1 << 16);
        accHi += __uint_as_float(u1 & 0xFFFF0000u);
        accLo += __uint_as_float(u2 << 16);
        accHi += __uint_as_float(u2 & 0xFFFF0000u);
        accLo += __uint_as_float(u3 << 16);
        accHi += __uint_as_float(u3 & 0xFFFF0000u);
        e = en;
    }
    accLo += __shfl_xor(accLo, 16, 64);
    accHi += __shfl_xor(accHi, 16, 64);
    accLo += __shfl_xor(accLo, 32, 64);
    accHi += __shfl_xor(accHi, 32, 64);
    if (sub == 0) {
        float di = dinv[wid];
        float rLo = fmaxf(fmaf(accLo, di, b[2 * fp]), 0.f);
        float rHi = fmaxf(fmaf(accHi, di, b[2 * fp + 1]), 0.f);
        unsigned out = (unsigned)f2bf(rLo) | ((unsigned)f2bf(rHi) << 16);
        ((unsigned*)hout)[(size_t)wid * 16 + fp] = out;
    }
}

// ---------------- pooling (bf16 in): register-segment accumulate -> LDS bins ----
__global__ void k_pool2(const unsigned short* __restrict__ h, const int* __restrict__ batch,
                        float* __restrict__ gsum, float* __restrict__ gcnt) {
    __shared__ float lacc[POOL_GSPAN][HID];
    __shared__ float lcnt[POOL_GSPAN];
    __shared__ int s_gmin;
    const int chunk_start = blockIdx.x * POOL_CHUNK;

    for (int j = threadIdx.x; j < POOL_GSPAN * HID; j += 256) ((float*)lacc)[j] = 0.f;
    if (threadIdx.x < POOL_GSPAN) lcnt[threadIdx.x] = 0.f;
    if (threadIdx.x == 0) {
        int cs = chunk_start < NN ? chunk_start : NN - 1;
        s_gmin = batch[cs];
    }
    __syncthreads();
    const int gmin = s_gmin;

    const int seg = threadIdx.x >> 3;
    const int l = (threadIdx.x & 7) * 4;
    const int i0 = chunk_start + seg * POOL_SEG;

    float4 acc = {0.f, 0.f, 0.f, 0.f};
    float cnt = 0.f;
    int cur_g = -1;

    for (int k = 0; k < POOL_SEG; k++) {
        int i = i0 + k;
        if (i >= NN) break;
        int g = batch[i];
        if (g != cur_g) {
            if (cur_g >= 0) {
                int bin = cur_g - gmin;
                if (bin >= 0 && bin < POOL_GSPAN) {
                    atomicAdd(&lacc[bin][l + 0], acc.x);
                    atomicAdd(&lacc[bin][l + 1], acc.y);
                    atomicAdd(&lacc[bin][l + 2], acc.z);
                    atomicAdd(&lacc[bin][l + 3], acc.w);
                    if (l == 0) atomicAdd(&lcnt[bin], cnt);
                } else {
                    atomicAdd(&gsum[cur_g * HID + l + 0], acc.x);
                    atomicAdd(&gsum[cur_g * HID + l + 1], acc.y);
                    atomicAdd(&gsum[cur_g * HID + l + 2], acc.z);
                    atomicAdd(&gsum[cur_g * HID + l + 3], acc.w);
                    if (l == 0) atomicAdd(&gcnt[cur_g], cnt);
                }
            }
            cur_g = g;
            acc.x = acc.y = acc.z = acc.w = 0.f;
            cnt = 0.f;
        }
        const ushort4 v = *(const ushort4*)&h[(size_t)i * HID + l];
        acc.x += bf2f(v.x); acc.y += bf2f(v.y);
        acc.z += bf2f(v.z); acc.w += bf2f(v.w);
        cnt += 1.f;
    }
    if (cur_g >= 0) {
        int bin = cur_g - gmin;
        if (bin >= 0 && bin < POOL_GSPAN) {
            atomicAdd(&lacc[bin][l + 0], acc.x);
            atomicAdd(&lacc[bin][l + 1], acc.y);
            atomicAdd(&lacc[bin][l + 2], acc.z);
            atomicAdd(&lacc[bin][l + 3], acc.w);
            if (l == 0) atomicAdd(&lcnt[bin], cnt);
        } else {
            atomicAdd(&gsum[cur_g * HID + l + 0], acc.x);
            atomicAdd(&gsum[cur_g * HID + l + 1], acc.y);
            atomicAdd(&gsum[cur_g * HID + l + 2], acc.z);
            atomicAdd(&gsum[cur_g * HID + l + 3], acc.w);
            if (l == 0) atomicAdd(&gcnt[cur_g], cnt);
        }
    }
    __syncthreads();

    for (int j = threadIdx.x; j < POOL_GSPAN * HID; j += 256) {
        int bin = j / HID, f = j % HID;
        int g = gmin + bin;
        float v = lacc[bin][f];
        if (g < NG && v != 0.f) atomicAdd(&gsum[g * HID + f], v);
    }
    if (threadIdx.x < POOL_GSPAN) {
        int g = gmin + threadIdx.x;
        float c = lcnt[threadIdx.x];
        if (g < NG && c != 0.f) atomicAdd(&gcnt[g], c);
    }
}

// ---------------- classifier + log_softmax ----------------
__global__ void k_classify(const float* __restrict__ gsum, const float* __restrict__ gcnt,
                           const float* __restrict__ Wl, const float* __restrict__ bl,
                           float* __restrict__ out) {
    __shared__ float w[HID * NCLS];
    __shared__ float bb[NCLS];
    int t = threadIdx.x;
    for (int j = t; j < HID * NCLS; j += blockDim.x) w[j] = Wl[j];
    if (t < NCLS) bb[t] = bl[t];
    __syncthreads();
    if (t >= NG) return;
    float c = gcnt[t];
    c = c > 1.f ? c : 1.f;
    float p[HID];
#pragma unroll
    for (int k = 0; k < HID; k++) p[k] = gsum[t * HID + k] / c;
    float lg[NCLS];
    float m = -1e30f;
#pragma unroll
    for (int c2 = 0; c2 < NCLS; c2++) {
        float a = bb[c2];
#pragma unroll
        for (int k = 0; k < HID; k++) a = fmaf(p[k], w[k * NCLS + c2], a);
        a = a > 0.f ? a : 0.f;
        lg[c2] = a;
        m = fmaxf(m, a);
    }
    float s = 0.f;
#pragma unroll
    for (int c2 = 0; c2 < NCLS; c2++) s += expf(lg[c2] - m);
    float ls = logf(s);
#pragma unroll
    for (int c2 = 0; c2 < NCLS; c2++) out[t * NCLS + c2] = lg[c2] - m - ls;
}

extern "C" void kernel_launch(void* const* d_in, const int* in_sizes, int n_in,
                              void* d_out, int out_size, void* d_ws, size_t ws_size,
                              hipStream_t stream) {
    const float* x  = (const float*)d_in[0];
    const int* ei   = (const int*)d_in[1];
    const int* batch = (const int*)d_in[2];
    const float* W0 = (const float*)d_in[3];
    const float* b0 = (const float*)d_in[4];
    const float* W1 = (const float*)d_in[5];
    const float* b1 = (const float*)d_in[6];
    const float* W2 = (const float*)d_in[7];
    const float* b2 = (const float*)d_in[8];
    const float* Wl = (const float*)d_in[9];
    const float* bl = (const float*)d_in[10];
    float* out = (float*)d_out;

    const int* esrc = ei;
    const int* edst = ei + NE;

    char* ws = (char*)d_ws;
    size_t off = 0;
    auto alloc = [&](size_t bytes) -> void* {
        void* p = ws + off;
        off = (off + bytes + 511) & ~(size_t)511;
        return p;
    };
    int*   row_ptr = (int*)alloc((NN + 1) * sizeof(int));
    float* dinv    = (float*)alloc(NN * sizeof(float));
    int*   deg     = (int*)alloc(NN * sizeof(int));
    int*   bsum    = (int*)alloc(256 * sizeof(int));
    int*   csr_src = (int*)alloc((size_t)NEP * sizeof(int));
    unsigned short* tbuf = (unsigned short*)alloc((size_t)(NN + 1) * HID * sizeof(unsigned short));
    unsigned short* hA   = (unsigned short*)alloc((size_t)(NN + 1) * HID * sizeof(unsigned short));
    float* gsum    = (float*)alloc(NG * HID * sizeof(float));
    float* gcnt    = (float*)alloc(NG * sizeof(float));
    (void)ws_size; (void)in_sizes; (void)n_in; (void)out_size;

    // u8 partial [NSL][NN] (3.2 MB) aliases tbuf rows 0..NN-1 (6.4 MB) — dead
    // until CSR done; zero pad-rows (written by k_init) are beyond the alias.
    unsigned char* partial = (unsigned char*)tbuf;
    unsigned short* tzero = tbuf + (size_t)NN * HID;
    unsigned short* hzero = hA + (size_t)NN * HID;

    // ---- CSR build: zero per-edge global atomics; rows padded to 16 ----
    k_init<<<17, 256, 0, stream>>>(gsum, gcnt, tzero, hzero);
    k_hist3<<<CSRGRID, CSR_T, 0, stream>>>(edst, partial);
    k_scanA<<<NB, SCAN_B, 0, stream>>>(partial, row_ptr, bsum, dinv, deg);
    k_scanB<<<1, 128, 0, stream>>>(bsum);
    k_scanC<<<NB, SCAN_B, 0, stream>>>(row_ptr, bsum, deg, csr_src);
    k_scat3<<<CSRGRID, CSR_T, 0, stream>>>(esrc, edst, row_ptr, partial, csr_src);

    // ---- layer 0 GEMM (MFMA) -> t0 ----
    k_gemm0<<<G0_GRID, 256, 0, stream>>>(x, W0, dinv, tbuf);
    // ---- agg0 fused with layer-1 GEMM (MFMA epilogue): t0 -> t1 (hA) ----
    k_aggf<<<AGF_GRID, 1024, 0, stream>>>(tbuf, row_ptr, csr_src, dinv, b0, W1, hA);
    // ---- agg1 fused with layer-2 GEMM (MFMA epilogue): t1 -> t2 (tbuf) ----
    k_aggf<<<AGF_GRID, 1024, 0, stream>>>(hA, row_ptr, csr_src, dinv, b1, W2, tbuf);
    // ---- agg2 (final): t2 -> h3 (hA) ----
    k_agga<<<AGG_GRID, 256, 0, stream>>>(tbuf, row_ptr, csr_src, dinv, b2, hA);

    // ---- pooling + classifier ----
    k_pool2<<<POOL_GRID, 256, 0, stream>>>(hA, batch, gsum, gcnt);
    k_classify<<<1, 128, 0, stream>>>(gsum, gcnt, Wl, bl, out);
}